// Round 1
// baseline (139.002 us; speedup 1.0000x reference)
//
#include <hip/hip_runtime.h>
#include <hip/hip_bf16.h>

// Problem constants
#define BB 2
#define TT 2048
#define DD 512
#define HH 8
#define DH 64
#define INNER 512
#define MAXLAG 5

typedef __attribute__((ext_vector_type(8))) short short8;
typedef __attribute__((ext_vector_type(4))) float floatx4;
typedef unsigned short ushort_t;

__device__ inline unsigned short f2bf(float f) {
    unsigned u = __float_as_uint(f);
    unsigned r = (u + 0x7FFFu + ((u >> 16) & 1u)) >> 16;
    return (unsigned short)r;
}
__device__ inline float bf2f(unsigned short u) {
    return __uint_as_float(((unsigned)u) << 16);
}

// Async global->LDS 16B (global_load_lds_dwordx4). LDS dest is wave-uniform
// base + lane*16 -- LDS layout must be lane-linear in granule order.
__device__ __forceinline__ void gload16(ushort_t* lds, const ushort_t* g) {
    __builtin_amdgcn_global_load_lds(
        (const __attribute__((address_space(1))) void*)g,
        (__attribute__((address_space(3))) void*)lds, 16, 0, 0);
}

// ---------------------------------------------------------------------------
// Fused convert: blocks [0,1024): x -> bf16; blocks [1024,2048): weight
// transpose+convert via 32x32 LDS tile. Wq/Wk/Wv land in ONE fused buffer
// wqkvt[1536][512] (rows 0..511 = Wq^T, 512..1023 = Wk^T, 1024..1535 = Wv^T)
// so QKV is a single N=1536 GEMM. Wo^T stays separate.
// ---------------------------------------------------------------------------
__global__ __launch_bounds__(256)
void cvt_kernel(const float* __restrict__ x,
                const float* __restrict__ wq, const float* __restrict__ wk,
                const float* __restrict__ wv, const float* __restrict__ wo,
                ushort_t* __restrict__ xb,
                ushort_t* __restrict__ wqkvt, ushort_t* __restrict__ wot)
{
    __shared__ float T[32][33];
    const int bid = blockIdx.x;
    if (bid < 1024) {
        int off = (bid * 256 + threadIdx.x) * 8;
        float4 a = *(const float4*)&x[off];
        float4 b = *(const float4*)&x[off + 4];
        ushort_t t[8];
        t[0] = f2bf(a.x); t[1] = f2bf(a.y); t[2] = f2bf(a.z); t[3] = f2bf(a.w);
        t[4] = f2bf(b.x); t[5] = f2bf(b.y); t[6] = f2bf(b.z); t[7] = f2bf(b.w);
        *(uint4*)&xb[off] = *(const uint4*)t;
        return;
    }
    const int r = bid - 1024;
    const int z = r >> 8;
    const int tile = r & 255;
    const float* s = (z == 0) ? wq : (z == 1) ? wk : (z == 2) ? wv : wo;
    ushort_t*    d = (z < 3) ? (wqkvt + (size_t)z * 512 * 512) : wot;
    const int k0 = (tile & 15) * 32;
    const int n0 = (tile >> 4) * 32;
    {
        const int kk = threadIdx.x >> 3;
        const int n4 = (threadIdx.x & 7) * 4;
        float4 v = *(const float4*)&s[(size_t)(k0 + kk) * 512 + n0 + n4];
        T[kk][n4 + 0] = v.x; T[kk][n4 + 1] = v.y;
        T[kk][n4 + 2] = v.z; T[kk][n4 + 3] = v.w;
    }
    __syncthreads();
    {
        const int nn = threadIdx.x >> 3;
        const int k4 = (threadIdx.x & 7) * 4;
        ushort4 o;
        o.x = f2bf(T[k4 + 0][nn]); o.y = f2bf(T[k4 + 1][nn]);
        o.z = f2bf(T[k4 + 2][nn]); o.w = f2bf(T[k4 + 3][nn]);
        *(ushort4*)&d[(size_t)(n0 + nn) * 512 + k0 + k4] = o;
    }
}

// ---------------------------------------------------------------------------
// QKV GEMM: 128x64x32 tile, global_load_lds(16B) staging, fused N=1536.
// M=4096, K=512. Grid (24,32) = 768 blocks = 3/CU exactly (balanced).
// 4 waves in 2x2 over (128,64): each wave 64x32, acc[4][2] of 16x16 frags.
// LDS layout: granule g = row*4 + chunk at [g*16B] (lane-linear -> gload_lds
// compatible); frag reads are full-window b128, words/bank uniform.
// Epilogue: n<512 -> Q, n<1024 -> K (scalar bf16 stores, [m][512]);
// n>=1024 -> V TRANSPOSED [bh][d][t] as packed ushort4 along t.
// Block's 64-col range lies in exactly one region (512 % 64 == 0).
// ---------------------------------------------------------------------------
#define QM 128
#define QN 64
#define QKS 32

__global__ __launch_bounds__(256)
void gemm_qkv(const ushort_t* __restrict__ A, const ushort_t* __restrict__ Bw,
              ushort_t* __restrict__ q, ushort_t* __restrict__ k,
              ushort_t* __restrict__ vt)
{
    __shared__ ushort_t As[QM * QKS];   // 8 KB: granules 0..511
    __shared__ ushort_t Bs[QN * QKS];   // 4 KB: granules 0..255

    const int tid  = threadIdx.x;
    const int wave = tid >> 6;
    const int lane = tid & 63;
    const int quad = lane >> 4;
    const int l15  = lane & 15;
    const int wr   = wave >> 1;
    const int wc   = wave & 1;
    const int bm   = blockIdx.y * QM;
    const int bn   = blockIdx.x * QN;

    // A staging: wave w issues 2 calls; call j covers granules (w*2+j)*64+lane
    const int ga0 = wave * 128 + lane;           // j=0
    const int ga1 = ga0 + 64;                    // j=1
    const ushort_t* ap0 = &A[(size_t)(bm + (ga0 >> 2)) * DD + (ga0 & 3) * 8];
    const ushort_t* ap1 = &A[(size_t)(bm + (ga1 >> 2)) * DD + (ga1 & 3) * 8];
    // B staging: wave w covers granules w*64+lane
    const int gb = wave * 64 + lane;
    const ushort_t* bp = &Bw[(size_t)(bn + (gb >> 2)) * DD + (gb & 3) * 8];
    ushort_t* lA0 = &As[(size_t)(wave * 128) * 8];
    ushort_t* lA1 = lA0 + 64 * 8;
    ushort_t* lB  = &Bs[(size_t)(wave * 64) * 8];

    floatx4 acc[4][2];
#pragma unroll
    for (int i = 0; i < 4; ++i)
#pragma unroll
        for (int j = 0; j < 2; ++j) acc[i][j] = (floatx4){0.f, 0.f, 0.f, 0.f};

    for (int k0 = 0; k0 < DD; k0 += QKS) {
        __syncthreads();                 // previous tile's compute done
        gload16(lA0, ap0 + k0);
        gload16(lA1, ap1 + k0);
        gload16(lB,  bp  + k0);
        __syncthreads();                 // compiler drains vmcnt before barrier

        short8 af[4], bfr[2];
#pragma unroll
        for (int mt = 0; mt < 4; ++mt)
            af[mt] = *(const short8*)&As[(((wr * 64 + mt * 16 + l15) << 2) + quad) * 8];
#pragma unroll
        for (int nt = 0; nt < 2; ++nt)
            bfr[nt] = *(const short8*)&Bs[(((wc * 32 + nt * 16 + l15) << 2) + quad) * 8];
#pragma unroll
        for (int mt = 0; mt < 4; ++mt)
#pragma unroll
            for (int nt = 0; nt < 2; ++nt)
                acc[mt][nt] = __builtin_amdgcn_mfma_f32_16x16x32_bf16(
                    af[mt], bfr[nt], acc[mt][nt], 0, 0, 0);
    }

    const int z = bn >> 9;   // 0=Q, 1=K, 2=V (uniform per block)
    if (z == 2) {
#pragma unroll
        for (int mt = 0; mt < 4; ++mt) {
            const int m0 = bm + wr * 64 + mt * 16 + quad * 4;
            const int b  = m0 >> 11;
            const int t0 = m0 & 2047;
#pragma unroll
            for (int nt = 0; nt < 2; ++nt) {
                const int n  = bn + wc * 32 + nt * 16 + l15 - 1024;
                const int h  = n >> 6, dd = n & 63;
                ushort4 o;
                o.x = f2bf(acc[mt][nt][0]); o.y = f2bf(acc[mt][nt][1]);
                o.z = f2bf(acc[mt][nt][2]); o.w = f2bf(acc[mt][nt][3]);
                *(ushort4*)&vt[((size_t)((b * 8 + h) * 64 + dd)) * 2048 + t0] = o;
            }
        }
        return;
    }
    ushort_t* O = (z == 0) ? q : k;
    const int nb = bn - z * 512;
#pragma unroll
    for (int mt = 0; mt < 4; ++mt) {
#pragma unroll
        for (int nt = 0; nt < 2; ++nt) {
            const int n = nb + wc * 32 + nt * 16 + l15;
#pragma unroll
            for (int reg = 0; reg < 4; ++reg) {
                const int m = bm + wr * 64 + mt * 16 + quad * 4 + reg;
                O[(size_t)m * 512 + n] = f2bf(acc[mt][nt][reg]);
            }
        }
    }
}

// ---------------------------------------------------------------------------
// Projection GEMM: 64x64x32 (keeps 2 blocks/CU at the small (8,64) grid),
// staging upgraded to global_load_lds(16B): granule order is already g = tid
// linear, so the per-wave call (granules wave*64+lane) is a drop-in.
// M=4096, N=512, K=512, f32 out + bias.
// ---------------------------------------------------------------------------
__global__ __launch_bounds__(256)
void gemm_proj(const ushort_t* __restrict__ A, const ushort_t* __restrict__ Bw,
               float* __restrict__ O, const float* __restrict__ bias)
{
    __shared__ ushort_t As[64 * 32];
    __shared__ ushort_t Bs[64 * 32];

    const int tid  = threadIdx.x;
    const int wave = tid >> 6;
    const int lane = tid & 63;
    const int quad = lane >> 4;
    const int l15  = lane & 15;
    const int wr   = wave >> 1;
    const int wc   = wave & 1;
    const int bm   = blockIdx.y * 64;
    const int bn   = blockIdx.x * 64;

    const ushort_t* ap = &A[(size_t)(bm + (tid >> 2)) * INNER + (tid & 3) * 8];
    const ushort_t* bp = &Bw[(size_t)(bn + (tid >> 2)) * INNER + (tid & 3) * 8];
    ushort_t* lA = &As[(size_t)(wave * 64) * 8];
    ushort_t* lB = &Bs[(size_t)(wave * 64) * 8];

    floatx4 acc[2][2];
#pragma unroll
    for (int i = 0; i < 2; ++i)
#pragma unroll
        for (int j = 0; j < 2; ++j) acc[i][j] = (floatx4){0.f, 0.f, 0.f, 0.f};

    for (int k0 = 0; k0 < INNER; k0 += 32) {
        __syncthreads();
        gload16(lA, ap + k0);
        gload16(lB, bp + k0);
        __syncthreads();

        short8 af[2], bfr[2];
#pragma unroll
        for (int mt = 0; mt < 2; ++mt)
            af[mt] = *(const short8*)&As[(((wr * 32 + mt * 16 + l15) << 2) + quad) * 8];
#pragma unroll
        for (int nt = 0; nt < 2; ++nt)
            bfr[nt] = *(const short8*)&Bs[(((wc * 32 + nt * 16 + l15) << 2) + quad) * 8];
#pragma unroll
        for (int mt = 0; mt < 2; ++mt)
#pragma unroll
            for (int nt = 0; nt < 2; ++nt)
                acc[mt][nt] = __builtin_amdgcn_mfma_f32_16x16x32_bf16(
                    af[mt], bfr[nt], acc[mt][nt], 0, 0, 0);
    }

    float bv[2];
#pragma unroll
    for (int nt = 0; nt < 2; ++nt)
        bv[nt] = bias[bn + wc * 32 + nt * 16 + l15];
#pragma unroll
    for (int mt = 0; mt < 2; ++mt) {
#pragma unroll
        for (int nt = 0; nt < 2; ++nt) {
            const int n = bn + wc * 32 + nt * 16 + l15;
#pragma unroll
            for (int reg = 0; reg < 4; ++reg) {
                const int m = bm + wr * 32 + mt * 16 + quad * 4 + reg;
                O[(size_t)m * 512 + n] = acc[mt][nt][reg] + bv[nt];
            }
        }
    }
}

// ---------------------------------------------------------------------------
// MFMA flash attention (unchanged this round): K natural [t][inner], V
// pre-transposed [bh][d][t]. Chunk-swizzled LDS granules, 2-way K-split,
// fixed-max softmax.
// ---------------------------------------------------------------------------
#define PAD 72
#define MFIX 10.0f

__global__ __launch_bounds__(256)
void attn_mfma(const ushort_t* __restrict__ Qg,
               const ushort_t* __restrict__ Kg,
               const ushort_t* __restrict__ Vtg,
               const float* __restrict__ lagw,
               ushort_t* __restrict__ Opart,
               float* __restrict__ Lpart)
{
    __shared__ ushort_t Ks[64 * 8 * 8];
    __shared__ ushort_t Vts[64 * 8 * 8];
    __shared__ ushort_t Pl[4][16][PAD];

    const int tid  = threadIdx.x;
    const int wave = tid >> 6;
    const int lane = tid & 63;
    const int quad = lane >> 4;
    const int l15  = lane & 15;

    const int bh = blockIdx.y;
    const int b  = bh >> 3;
    const int h  = bh & 7;
    const int c  = blockIdx.x;
    const int qt = 31 - (c >> 1);
    const int sp = c & 1;
    const int i0 = qt * 64;
    const int h1 = (qt + 1) >> 1;
    const int lo = sp ? h1 : 0;
    const int hi = sp ? (qt + 1) : h1;

    float lagb[MAXLAG + 1];
    {
        float mx = -1e30f;
#pragma unroll
        for (int l = 0; l <= MAXLAG; ++l) {
            lagb[l] = lagw[h * (MAXLAG + 1) + l];
            mx = fmaxf(mx, lagb[l]);
        }
        float s = 0.f;
#pragma unroll
        for (int l = 0; l <= MAXLAG; ++l) { lagb[l] = __expf(lagb[l] - mx); s += lagb[l]; }
        float inv = 1.f / s;
#pragma unroll
        for (int l = 0; l <= MAXLAG; ++l) lagb[l] = lagb[l] * inv - MFIX;
    }
    const float c1  = 0.125f;
    const float c2f = lagb[MAXLAG];

    short8 qf0, qf1;
    {
        const ushort_t* qbase =
            Qg + ((size_t)(b * TT + i0 + wave * 16 + l15)) * INNER + h * DH;
        qf0 = *(const short8*)(qbase + quad * 8);
        qf1 = *(const short8*)(qbase + 32 + quad * 8);
    }

    floatx4 oacc[4];
    float lsum[4] = {0.f, 0.f, 0.f, 0.f};
#pragma unroll
    for (int cb = 0; cb < 4; ++cb) oacc[cb] = (floatx4){0.f, 0.f, 0.f, 0.f};

    const int ibase = i0 + wave * 16 + quad * 4;

    const int srow = tid >> 3;
    const int sc   = tid & 7;
    const ushort_t* Kp0 = Kg + ((size_t)(b * TT) + srow) * INNER + h * DH + sc * 8;
    const ushort_t* Kp1 = Kp0 + (size_t)32 * INNER;
    const ushort_t* Vp0 = Vtg + ((size_t)(bh * 64 + srow)) * 2048 + sc * 8;
    const ushort_t* Vp1 = Vp0 + (size_t)32 * 2048;
    const int slot = (sc + srow) & 7;
    const int kdst0 = ((srow << 3) + slot) << 3;
    const int kdst1 = (((srow + 32) << 3) + slot) << 3;

    uint4 pk0, pk1, pv0, pv1;
    if (lo < hi) {
        const size_t koff = (size_t)(lo * 64) * INNER;
        pk0 = *(const uint4*)(Kp0 + koff);
        pk1 = *(const uint4*)(Kp1 + koff);
        pv0 = *(const uint4*)(Vp0 + lo * 64);
        pv1 = *(const uint4*)(Vp1 + lo * 64);
    }

    for (int kt = lo; kt < hi; ++kt) {
        __syncthreads();
        *(uint4*)&Ks[kdst0]  = pk0;
        *(uint4*)&Ks[kdst1]  = pk1;
        *(uint4*)&Vts[kdst0] = pv0;
        *(uint4*)&Vts[kdst1] = pv1;
        if (kt + 1 < hi) {
            const size_t koff = (size_t)((kt + 1) * 64) * INNER;
            pk0 = *(const uint4*)(Kp0 + koff);
            pk1 = *(const uint4*)(Kp1 + koff);
            pv0 = *(const uint4*)(Vp0 + (kt + 1) * 64);
            pv1 = *(const uint4*)(Vp1 + (kt + 1) * 64);
        }
        __syncthreads();

        const int j0 = kt * 64;

        floatx4 sacc[4];
#pragma unroll
        for (int cb = 0; cb < 4; ++cb) {
            const int key = cb * 16 + l15;
            short8 kf0 = *(const short8*)&Ks[((key << 3) + ((quad + key) & 7)) << 3];
            short8 kf1 = *(const short8*)&Ks[((key << 3) + ((quad + 4 + key) & 7)) << 3];
            floatx4 zf = (floatx4){0.f, 0.f, 0.f, 0.f};
            zf = __builtin_amdgcn_mfma_f32_16x16x32_bf16(qf0, kf0, zf, 0, 0, 0);
            zf = __builtin_amdgcn_mfma_f32_16x16x32_bf16(qf1, kf1, zf, 0, 0, 0);
            sacc[cb] = zf;
        }

        float p[4][4];
        if (i0 + wave * 16 - (j0 + 63) >= MAXLAG) {
#pragma unroll
            for (int cb = 0; cb < 4; ++cb)
#pragma unroll
                for (int reg = 0; reg < 4; ++reg)
                    p[cb][reg] = __expf(fmaf(sacc[cb][reg], c1, c2f));
        } else {
#pragma unroll
            for (int cb = 0; cb < 4; ++cb) {
                const int j = j0 + cb * 16 + l15;
#pragma unroll
                for (int reg = 0; reg < 4; ++reg) {
                    const int lag = (ibase + reg) - j;
                    float bias = (lag <= 0) ? lagb[0]
                               : (lag == 1) ? lagb[1]
                               : (lag == 2) ? lagb[2]
                               : (lag == 3) ? lagb[3]
                               : (lag == 4) ? lagb[4] : lagb[5];
                    float e = __expf(fmaf(sacc[cb][reg], c1, bias));
                    p[cb][reg] = (lag < 0) ? 0.f : e;
                }
            }
        }
#pragma unroll
        for (int cb = 0; cb < 4; ++cb)
#pragma unroll
            for (int reg = 0; reg < 4; ++reg)
                lsum[reg] += p[cb][reg];

#pragma unroll
        for (int cb = 0; cb < 4; ++cb)
#pragma unroll
            for (int reg = 0; reg < 4; ++reg)
                Pl[wave][quad * 4 + reg][cb * 16 + l15] = f2bf(p[cb][reg]);

        short8 pf0 = *(const short8*)&Pl[wave][l15][quad * 8];
        short8 pf1 = *(const short8*)&Pl[wave][l15][32 + quad * 8];

#pragma unroll
        for (int cb = 0; cb < 4; ++cb) {
            const int dd = cb * 16 + l15;
            short8 vf0 = *(const short8*)&Vts[((dd << 3) + ((quad + dd) & 7)) << 3];
            short8 vf1 = *(const short8*)&Vts[((dd << 3) + ((quad + 4 + dd) & 7)) << 3];
            oacc[cb] = __builtin_amdgcn_mfma_f32_16x16x32_bf16(pf0, vf0, oacc[cb], 0, 0, 0);
            oacc[cb] = __builtin_amdgcn_mfma_f32_16x16x32_bf16(pf1, vf1, oacc[cb], 0, 0, 0);
        }
    }

#pragma unroll
    for (int reg = 0; reg < 4; ++reg) {
        lsum[reg] += __shfl_xor(lsum[reg], 1);
        lsum[reg] += __shfl_xor(lsum[reg], 2);
        lsum[reg] += __shfl_xor(lsum[reg], 4);
        lsum[reg] += __shfl_xor(lsum[reg], 8);
    }

#pragma unroll
    for (int reg = 0; reg < 4; ++reg) {
        const int row = ibase + reg;
        const size_t obase = ((size_t)(sp * 16 + bh) * TT + row) * 64;
#pragma unroll
        for (int cb = 0; cb < 4; ++cb)
            Opart[obase + cb * 16 + l15] = f2bf(oacc[cb][reg]);
        if (l15 == 0)
            Lpart[(size_t)(sp * 16 + bh) * TT + row] = lsum[reg];
    }
}

// ---------------------------------------------------------------------------
// Combine the 2 K-split partials -> ao bf16 [b*T+i][h*64+d]
// ---------------------------------------------------------------------------
#define CMB_UNITS (16 * TT * 16)

__global__ __launch_bounds__(256)
void combine_kernel(const ushort_t* __restrict__ Opart,
                    const float* __restrict__ Lpart,
                    ushort_t* __restrict__ ao)
{
    int u = blockIdx.x * 256 + threadIdx.x;
    const int bh  = u >> 15;
    const int rem = u & 32767;
    const int i   = rem >> 4;
    const int d   = (rem & 15) * 4;
    const int b   = bh >> 3;
    const int h   = bh & 7;

    const size_t p0 = ((size_t)bh * TT + i) * 64 + d;
    const size_t p1 = ((size_t)(16 + bh) * TT + i) * 64 + d;
    ushort4 a0 = *(const ushort4*)&Opart[p0];
    ushort4 a1 = *(const ushort4*)&Opart[p1];
    const float l = Lpart[(size_t)bh * TT + i] + Lpart[(size_t)(16 + bh) * TT + i];
    const float inv = 1.f / l;

    ushort4 o;
    o.x = f2bf((bf2f(a0.x) + bf2f(a1.x)) * inv);
    o.y = f2bf((bf2f(a0.y) + bf2f(a1.y)) * inv);
    o.z = f2bf((bf2f(a0.z) + bf2f(a1.z)) * inv);
    o.w = f2bf((bf2f(a0.w) + bf2f(a1.w)) * inv);
    *(ushort4*)&ao[((size_t)(b * TT + i)) * INNER + h * DH + d] = o;
}

// ---------------------------------------------------------------------------
extern "C" void kernel_launch(void* const* d_in, const int* in_sizes, int n_in,
                              void* d_out, int out_size, void* d_ws, size_t ws_size,
                              hipStream_t stream)
{
    const float* x  = (const float*)d_in[0];
    const float* Wq = (const float*)d_in[1];
    const float* Wk = (const float*)d_in[2];
    const float* Wv = (const float*)d_in[3];
    const float* Wo = (const float*)d_in[4];
    const float* bo = (const float*)d_in[5];
    const float* lw = (const float*)d_in[6];
    float* out = (float*)d_out;

    const size_t SZ  = (size_t)BB * TT * INNER;  // 2M elements
    const size_t NWE = (size_t)DD * INNER;       // 256K per weight
    ushort_t* xb    = (ushort_t*)d_ws;
    ushort_t* wqkvt = xb + SZ;                   // fused [1536][512]
    ushort_t* wot   = wqkvt + 3 * NWE;
    ushort_t* q     = wot + NWE;
    ushort_t* k     = q + SZ;
    ushort_t* vt    = k + SZ;                    // V TRANSPOSED [bh][d][t]
    ushort_t* opart = vt + SZ;                   // 2 slots * 16*TT*64
    float*    lpart = (float*)(opart + 2 * SZ);
    ushort_t* ao    = xb;                        // alias: xb dead after QKV

    cvt_kernel<<<2048, 256, 0, stream>>>(x, Wq, Wk, Wv, Wo, xb, wqkvt, wot);

    dim3 gQKV(3 * INNER / QN, (BB * TT) / QM);   // (24, 32) = 768 blocks
    gemm_qkv<<<gQKV, 256, 0, stream>>>(xb, wqkvt, q, k, vt);

    dim3 gATT(64, BB * HH);
    attn_mfma<<<gATT, 256, 0, stream>>>(q, k, vt, lw, opart, lpart);

    combine_kernel<<<CMB_UNITS / 256, 256, 0, stream>>>(opart, lpart, ao);

    dim3 gPRJ(DD / 64, (BB * TT) / 64);          // (8, 64) = 512 blocks
    gemm_proj<<<gPRJ, 256, 0, stream>>>(ao, wot, out, bo);
}

// Round 2
// 130.069 us; speedup vs baseline: 1.0687x; 1.0687x over previous
//
#include <hip/hip_runtime.h>
#include <hip/hip_bf16.h>

// Problem constants
#define BB 2
#define TT 2048
#define DD 512
#define HH 8
#define DH 64
#define INNER 512
#define MAXLAG 5

typedef __attribute__((ext_vector_type(8))) short short8;
typedef __attribute__((ext_vector_type(4))) float floatx4;
typedef unsigned short ushort_t;

__device__ inline unsigned short f2bf(float f) {
    unsigned u = __float_as_uint(f);
    unsigned r = (u + 0x7FFFu + ((u >> 16) & 1u)) >> 16;
    return (unsigned short)r;
}
__device__ inline float bf2f(unsigned short u) {
    return __uint_as_float(((unsigned)u) << 16);
}

// Async global->LDS 16B (global_load_lds_dwordx4). LDS dest is wave-uniform
// base + lane*16 -- LDS layout must be lane-linear in granule order.
__device__ __forceinline__ void gload16(ushort_t* lds, const ushort_t* g) {
    __builtin_amdgcn_global_load_lds(
        (const __attribute__((address_space(1))) void*)g,
        (__attribute__((address_space(3))) void*)lds, 16, 0, 0);
}

// ---------------------------------------------------------------------------
// Fused convert: blocks [0,1024): x -> bf16; blocks [1024,2048): weight
// transpose+convert via 32x32 LDS tile. Wq/Wk/Wv land in ONE fused buffer
// wqkvt[1536][512]; Wo^T separate.
// ---------------------------------------------------------------------------
__global__ __launch_bounds__(256)
void cvt_kernel(const float* __restrict__ x,
                const float* __restrict__ wq, const float* __restrict__ wk,
                const float* __restrict__ wv, const float* __restrict__ wo,
                ushort_t* __restrict__ xb,
                ushort_t* __restrict__ wqkvt, ushort_t* __restrict__ wot)
{
    __shared__ float T[32][33];
    const int bid = blockIdx.x;
    if (bid < 1024) {
        int off = (bid * 256 + threadIdx.x) * 8;
        float4 a = *(const float4*)&x[off];
        float4 b = *(const float4*)&x[off + 4];
        ushort_t t[8];
        t[0] = f2bf(a.x); t[1] = f2bf(a.y); t[2] = f2bf(a.z); t[3] = f2bf(a.w);
        t[4] = f2bf(b.x); t[5] = f2bf(b.y); t[6] = f2bf(b.z); t[7] = f2bf(b.w);
        *(uint4*)&xb[off] = *(const uint4*)t;
        return;
    }
    const int r = bid - 1024;
    const int z = r >> 8;
    const int tile = r & 255;
    const float* s = (z == 0) ? wq : (z == 1) ? wk : (z == 2) ? wv : wo;
    ushort_t*    d = (z < 3) ? (wqkvt + (size_t)z * 512 * 512) : wot;
    const int k0 = (tile & 15) * 32;
    const int n0 = (tile >> 4) * 32;
    {
        const int kk = threadIdx.x >> 3;
        const int n4 = (threadIdx.x & 7) * 4;
        float4 v = *(const float4*)&s[(size_t)(k0 + kk) * 512 + n0 + n4];
        T[kk][n4 + 0] = v.x; T[kk][n4 + 1] = v.y;
        T[kk][n4 + 2] = v.z; T[kk][n4 + 3] = v.w;
    }
    __syncthreads();
    {
        const int nn = threadIdx.x >> 3;
        const int k4 = (threadIdx.x & 7) * 4;
        ushort4 o;
        o.x = f2bf(T[k4 + 0][nn]); o.y = f2bf(T[k4 + 1][nn]);
        o.z = f2bf(T[k4 + 2][nn]); o.w = f2bf(T[k4 + 3][nn]);
        *(ushort4*)&d[(size_t)(n0 + nn) * 512 + k0 + k4] = o;
    }
}

// ---------------------------------------------------------------------------
// QKV GEMM: 128x64 tile, BK=64 (8 K-steps: half the barrier/vmcnt drains of
// BK=32), global_load_lds(16B) staging, fused N=1536. Grid (24,32)=768=3/CU.
// LDS 24KB. Granule g = row*8 + chunk (16B each), lane-linear for gload_lds;
// staging is 128B-contiguous per row (8 lanes/row). Frag reads b128.
// Epilogue: z=0 -> Q, z=1 -> K (scalar bf16, [m][512]); z=2 -> V^T
// [bh][d][t] packed ushort4 along t.
// ---------------------------------------------------------------------------
#define QM 128
#define QN 64
#define QKS 64

__global__ __launch_bounds__(256)
void gemm_qkv(const ushort_t* __restrict__ A, const ushort_t* __restrict__ Bw,
              ushort_t* __restrict__ q, ushort_t* __restrict__ k,
              ushort_t* __restrict__ vt)
{
    __shared__ ushort_t As[QM * QKS];   // 16 KB: granules 0..1023
    __shared__ ushort_t Bs[QN * QKS];   // 8 KB:  granules 0..511

    const int tid  = threadIdx.x;
    const int wave = tid >> 6;
    const int lane = tid & 63;
    const int quad = lane >> 4;
    const int l15  = lane & 15;
    const int wr   = wave >> 1;
    const int wc   = wave & 1;
    const int bm   = blockIdx.y * QM;
    const int bn   = blockIdx.x * QN;

    // A staging: wave w issues 4 calls; call j covers granules w*256+j*64+lane
    const int ga = wave * 256 + lane;
    const ushort_t* ap0 = &A[(size_t)(bm + ((ga +   0) >> 3)) * DD + ((ga +   0) & 7) * 8];
    const ushort_t* ap1 = &A[(size_t)(bm + ((ga +  64) >> 3)) * DD + ((ga +  64) & 7) * 8];
    const ushort_t* ap2 = &A[(size_t)(bm + ((ga + 128) >> 3)) * DD + ((ga + 128) & 7) * 8];
    const ushort_t* ap3 = &A[(size_t)(bm + ((ga + 192) >> 3)) * DD + ((ga + 192) & 7) * 8];
    // B staging: wave w issues 2 calls; call j covers granules w*128+j*64+lane
    const int gb = wave * 128 + lane;
    const ushort_t* bp0 = &Bw[(size_t)(bn + ((gb +  0) >> 3)) * DD + ((gb +  0) & 7) * 8];
    const ushort_t* bp1 = &Bw[(size_t)(bn + ((gb + 64) >> 3)) * DD + ((gb + 64) & 7) * 8];
    ushort_t* lA0 = &As[(size_t)(wave * 256 +   0) * 8];
    ushort_t* lA1 = &As[(size_t)(wave * 256 +  64) * 8];
    ushort_t* lA2 = &As[(size_t)(wave * 256 + 128) * 8];
    ushort_t* lA3 = &As[(size_t)(wave * 256 + 192) * 8];
    ushort_t* lB0 = &Bs[(size_t)(wave * 128 +  0) * 8];
    ushort_t* lB1 = &Bs[(size_t)(wave * 128 + 64) * 8];

    floatx4 acc[4][2];
#pragma unroll
    for (int i = 0; i < 4; ++i)
#pragma unroll
        for (int j = 0; j < 2; ++j) acc[i][j] = (floatx4){0.f, 0.f, 0.f, 0.f};

    for (int k0 = 0; k0 < DD; k0 += QKS) {
        __syncthreads();                 // previous tile's frag reads done
        gload16(lA0, ap0 + k0);
        gload16(lA1, ap1 + k0);
        gload16(lA2, ap2 + k0);
        gload16(lA3, ap3 + k0);
        gload16(lB0, bp0 + k0);
        gload16(lB1, bp1 + k0);
        __syncthreads();                 // compiler drains vmcnt before barrier

#pragma unroll
        for (int kk = 0; kk < 2; ++kk) {
            short8 af[4], bfr[2];
#pragma unroll
            for (int mt = 0; mt < 4; ++mt)
                af[mt] = *(const short8*)
                    &As[(((wr * 64 + mt * 16 + l15) << 3) + (kk << 2) + quad) * 8];
#pragma unroll
            for (int nt = 0; nt < 2; ++nt)
                bfr[nt] = *(const short8*)
                    &Bs[(((wc * 32 + nt * 16 + l15) << 3) + (kk << 2) + quad) * 8];
#pragma unroll
            for (int mt = 0; mt < 4; ++mt)
#pragma unroll
                for (int nt = 0; nt < 2; ++nt)
                    acc[mt][nt] = __builtin_amdgcn_mfma_f32_16x16x32_bf16(
                        af[mt], bfr[nt], acc[mt][nt], 0, 0, 0);
        }
    }

    const int z = bn >> 9;   // 0=Q, 1=K, 2=V (uniform per block)
    if (z == 2) {
#pragma unroll
        for (int mt = 0; mt < 4; ++mt) {
            const int m0 = bm + wr * 64 + mt * 16 + quad * 4;
            const int b  = m0 >> 11;
            const int t0 = m0 & 2047;
#pragma unroll
            for (int nt = 0; nt < 2; ++nt) {
                const int n  = bn + wc * 32 + nt * 16 + l15 - 1024;
                const int h  = n >> 6, dd = n & 63;
                ushort4 o;
                o.x = f2bf(acc[mt][nt][0]); o.y = f2bf(acc[mt][nt][1]);
                o.z = f2bf(acc[mt][nt][2]); o.w = f2bf(acc[mt][nt][3]);
                *(ushort4*)&vt[((size_t)((b * 8 + h) * 64 + dd)) * 2048 + t0] = o;
            }
        }
        return;
    }
    ushort_t* O = (z == 0) ? q : k;
    const int nb = bn - z * 512;
#pragma unroll
    for (int mt = 0; mt < 4; ++mt) {
#pragma unroll
        for (int nt = 0; nt < 2; ++nt) {
            const int n = nb + wc * 32 + nt * 16 + l15;
#pragma unroll
            for (int reg = 0; reg < 4; ++reg) {
                const int m = bm + wr * 64 + mt * 16 + quad * 4 + reg;
                O[(size_t)m * 512 + n] = f2bf(acc[mt][nt][reg]);
            }
        }
    }
}

// ---------------------------------------------------------------------------
// Projection GEMM: 64x64, BK=64 (8 K-steps), gload_lds staging. LDS 16KB.
// M=4096, N=512, K=512, f32 out + bias.
// ---------------------------------------------------------------------------
__global__ __launch_bounds__(256)
void gemm_proj(const ushort_t* __restrict__ A, const ushort_t* __restrict__ Bw,
               float* __restrict__ O, const float* __restrict__ bias)
{
    __shared__ ushort_t As[64 * 64];
    __shared__ ushort_t Bs[64 * 64];

    const int tid  = threadIdx.x;
    const int wave = tid >> 6;
    const int lane = tid & 63;
    const int quad = lane >> 4;
    const int l15  = lane & 15;
    const int wr   = wave >> 1;
    const int wc   = wave & 1;
    const int bm   = blockIdx.y * 64;
    const int bn   = blockIdx.x * 64;

    const int g0 = wave * 128 + lane;
    const ushort_t* ap0 = &A[(size_t)(bm + ((g0 +  0) >> 3)) * INNER + ((g0 +  0) & 7) * 8];
    const ushort_t* ap1 = &A[(size_t)(bm + ((g0 + 64) >> 3)) * INNER + ((g0 + 64) & 7) * 8];
    const ushort_t* bp0 = &Bw[(size_t)(bn + ((g0 +  0) >> 3)) * INNER + ((g0 +  0) & 7) * 8];
    const ushort_t* bp1 = &Bw[(size_t)(bn + ((g0 + 64) >> 3)) * INNER + ((g0 + 64) & 7) * 8];
    ushort_t* lA0 = &As[(size_t)(wave * 128 +  0) * 8];
    ushort_t* lA1 = &As[(size_t)(wave * 128 + 64) * 8];
    ushort_t* lB0 = &Bs[(size_t)(wave * 128 +  0) * 8];
    ushort_t* lB1 = &Bs[(size_t)(wave * 128 + 64) * 8];

    floatx4 acc[2][2];
#pragma unroll
    for (int i = 0; i < 2; ++i)
#pragma unroll
        for (int j = 0; j < 2; ++j) acc[i][j] = (floatx4){0.f, 0.f, 0.f, 0.f};

    for (int k0 = 0; k0 < INNER; k0 += 64) {
        __syncthreads();
        gload16(lA0, ap0 + k0);
        gload16(lA1, ap1 + k0);
        gload16(lB0, bp0 + k0);
        gload16(lB1, bp1 + k0);
        __syncthreads();

#pragma unroll
        for (int kk = 0; kk < 2; ++kk) {
            short8 af[2], bfr[2];
#pragma unroll
            for (int mt = 0; mt < 2; ++mt)
                af[mt] = *(const short8*)
                    &As[(((wr * 32 + mt * 16 + l15) << 3) + (kk << 2) + quad) * 8];
#pragma unroll
            for (int nt = 0; nt < 2; ++nt)
                bfr[nt] = *(const short8*)
                    &Bs[(((wc * 32 + nt * 16 + l15) << 3) + (kk << 2) + quad) * 8];
#pragma unroll
            for (int mt = 0; mt < 2; ++mt)
#pragma unroll
                for (int nt = 0; nt < 2; ++nt)
                    acc[mt][nt] = __builtin_amdgcn_mfma_f32_16x16x32_bf16(
                        af[mt], bfr[nt], acc[mt][nt], 0, 0, 0);
        }
    }

    float bv[2];
#pragma unroll
    for (int nt = 0; nt < 2; ++nt)
        bv[nt] = bias[bn + wc * 32 + nt * 16 + l15];
#pragma unroll
    for (int mt = 0; mt < 2; ++mt) {
#pragma unroll
        for (int nt = 0; nt < 2; ++nt) {
            const int n = bn + wc * 32 + nt * 16 + l15;
#pragma unroll
            for (int reg = 0; reg < 4; ++reg) {
                const int m = bm + wr * 32 + mt * 16 + quad * 4 + reg;
                O[(size_t)m * 512 + n] = acc[mt][nt][reg] + bv[nt];
            }
        }
    }
}

// ---------------------------------------------------------------------------
// MFMA flash attention, UNSPLIT (no K-split, no combine kernel): each block
// owns one (qt, bh), iterates kt = 0..qt, normalizes by 1/lsum in the
// epilogue and writes ao directly. Grid = 512 blocks = exactly 2/CU, all
// co-resident. Balance: flat id f and f+256 land on the same CU under
// round-robin XCD dispatch, so map them to qt and 31-qt -> every CU pair
// does exactly 33 kt-iterations (the ideal mean).
// ---------------------------------------------------------------------------
#define PAD 72
#define MFIX 10.0f

__global__ __launch_bounds__(256)
void attn_mfma(const ushort_t* __restrict__ Qg,
               const ushort_t* __restrict__ Kg,
               const ushort_t* __restrict__ Vtg,
               const float* __restrict__ lagw,
               ushort_t* __restrict__ ao)
{
    __shared__ ushort_t Ks[64 * 8 * 8];
    __shared__ ushort_t Vts[64 * 8 * 8];
    __shared__ ushort_t Pl[4][16][PAD];

    const int tid  = threadIdx.x;
    const int wave = tid >> 6;
    const int lane = tid & 63;
    const int quad = lane >> 4;
    const int l15  = lane & 15;

    // pair-balanced (qt, bh) mapping
    const int f    = blockIdx.x + 32 * blockIdx.y;   // gridDim (32,16)
    const int half = f >> 8;
    const int r    = f & 255;
    const int bh   = (half << 3) | (r >> 5);
    const int qt   = half ? (r & 31) : (31 - (r & 31));
    const int b    = bh >> 3;
    const int h    = bh & 7;
    const int i0   = qt * 64;
    const int hi   = qt + 1;

    float lagb[MAXLAG + 1];
    {
        float mx = -1e30f;
#pragma unroll
        for (int l = 0; l <= MAXLAG; ++l) {
            lagb[l] = lagw[h * (MAXLAG + 1) + l];
            mx = fmaxf(mx, lagb[l]);
        }
        float s = 0.f;
#pragma unroll
        for (int l = 0; l <= MAXLAG; ++l) { lagb[l] = __expf(lagb[l] - mx); s += lagb[l]; }
        float inv = 1.f / s;
#pragma unroll
        for (int l = 0; l <= MAXLAG; ++l) lagb[l] = lagb[l] * inv - MFIX;
    }
    const float c1  = 0.125f;
    const float c2f = lagb[MAXLAG];

    short8 qf0, qf1;
    {
        const ushort_t* qbase =
            Qg + ((size_t)(b * TT + i0 + wave * 16 + l15)) * INNER + h * DH;
        qf0 = *(const short8*)(qbase + quad * 8);
        qf1 = *(const short8*)(qbase + 32 + quad * 8);
    }

    floatx4 oacc[4];
    float lsum[4] = {0.f, 0.f, 0.f, 0.f};
#pragma unroll
    for (int cb = 0; cb < 4; ++cb) oacc[cb] = (floatx4){0.f, 0.f, 0.f, 0.f};

    const int ibase = i0 + wave * 16 + quad * 4;

    const int srow = tid >> 3;
    const int sc   = tid & 7;
    const ushort_t* Kp0 = Kg + ((size_t)(b * TT) + srow) * INNER + h * DH + sc * 8;
    const ushort_t* Kp1 = Kp0 + (size_t)32 * INNER;
    const ushort_t* Vp0 = Vtg + ((size_t)(bh * 64 + srow)) * 2048 + sc * 8;
    const ushort_t* Vp1 = Vp0 + (size_t)32 * 2048;
    const int slot = (sc + srow) & 7;
    const int kdst0 = ((srow << 3) + slot) << 3;
    const int kdst1 = (((srow + 32) << 3) + slot) << 3;

    uint4 pk0 = *(const uint4*)Kp0;
    uint4 pk1 = *(const uint4*)Kp1;
    uint4 pv0 = *(const uint4*)Vp0;
    uint4 pv1 = *(const uint4*)Vp1;

    for (int kt = 0; kt < hi; ++kt) {
        __syncthreads();
        *(uint4*)&Ks[kdst0]  = pk0;
        *(uint4*)&Ks[kdst1]  = pk1;
        *(uint4*)&Vts[kdst0] = pv0;
        *(uint4*)&Vts[kdst1] = pv1;
        if (kt + 1 < hi) {
            const size_t koff = (size_t)((kt + 1) * 64) * INNER;
            pk0 = *(const uint4*)(Kp0 + koff);
            pk1 = *(const uint4*)(Kp1 + koff);
            pv0 = *(const uint4*)(Vp0 + (kt + 1) * 64);
            pv1 = *(const uint4*)(Vp1 + (kt + 1) * 64);
        }
        __syncthreads();

        const int j0 = kt * 64;

        floatx4 sacc[4];
#pragma unroll
        for (int cb = 0; cb < 4; ++cb) {
            const int key = cb * 16 + l15;
            short8 kf0 = *(const short8*)&Ks[((key << 3) + ((quad + key) & 7)) << 3];
            short8 kf1 = *(const short8*)&Ks[((key << 3) + ((quad + 4 + key) & 7)) << 3];
            floatx4 zf = (floatx4){0.f, 0.f, 0.f, 0.f};
            zf = __builtin_amdgcn_mfma_f32_16x16x32_bf16(qf0, kf0, zf, 0, 0, 0);
            zf = __builtin_amdgcn_mfma_f32_16x16x32_bf16(qf1, kf1, zf, 0, 0, 0);
            sacc[cb] = zf;
        }

        float p[4][4];
        if (i0 + wave * 16 - (j0 + 63) >= MAXLAG) {
#pragma unroll
            for (int cb = 0; cb < 4; ++cb)
#pragma unroll
                for (int reg = 0; reg < 4; ++reg)
                    p[cb][reg] = __expf(fmaf(sacc[cb][reg], c1, c2f));
        } else {
#pragma unroll
            for (int cb = 0; cb < 4; ++cb) {
                const int j = j0 + cb * 16 + l15;
#pragma unroll
                for (int reg = 0; reg < 4; ++reg) {
                    const int lag = (ibase + reg) - j;
                    float bias = (lag <= 0) ? lagb[0]
                               : (lag == 1) ? lagb[1]
                               : (lag == 2) ? lagb[2]
                               : (lag == 3) ? lagb[3]
                               : (lag == 4) ? lagb[4] : lagb[5];
                    float e = __expf(fmaf(sacc[cb][reg], c1, bias));
                    p[cb][reg] = (lag < 0) ? 0.f : e;
                }
            }
        }
#pragma unroll
        for (int cb = 0; cb < 4; ++cb)
#pragma unroll
            for (int reg = 0; reg < 4; ++reg)
                lsum[reg] += p[cb][reg];

#pragma unroll
        for (int cb = 0; cb < 4; ++cb)
#pragma unroll
            for (int reg = 0; reg < 4; ++reg)
                Pl[wave][quad * 4 + reg][cb * 16 + l15] = f2bf(p[cb][reg]);

        short8 pf0 = *(const short8*)&Pl[wave][l15][quad * 8];
        short8 pf1 = *(const short8*)&Pl[wave][l15][32 + quad * 8];

#pragma unroll
        for (int cb = 0; cb < 4; ++cb) {
            const int dd = cb * 16 + l15;
            short8 vf0 = *(const short8*)&Vts[((dd << 3) + ((quad + dd) & 7)) << 3];
            short8 vf1 = *(const short8*)&Vts[((dd << 3) + ((quad + 4 + dd) & 7)) << 3];
            oacc[cb] = __builtin_amdgcn_mfma_f32_16x16x32_bf16(pf0, vf0, oacc[cb], 0, 0, 0);
            oacc[cb] = __builtin_amdgcn_mfma_f32_16x16x32_bf16(pf1, vf1, oacc[cb], 0, 0, 0);
        }
    }

#pragma unroll
    for (int reg = 0; reg < 4; ++reg) {
        lsum[reg] += __shfl_xor(lsum[reg], 1);
        lsum[reg] += __shfl_xor(lsum[reg], 2);
        lsum[reg] += __shfl_xor(lsum[reg], 4);
        lsum[reg] += __shfl_xor(lsum[reg], 8);
    }

#pragma unroll
    for (int reg = 0; reg < 4; ++reg) {
        const int row = ibase + reg;
        const float inv = 1.f / lsum[reg];
        ushort_t* dst = &ao[((size_t)(b * TT + row)) * INNER + h * DH];
#pragma unroll
        for (int cb = 0; cb < 4; ++cb)
            dst[cb * 16 + l15] = f2bf(oacc[cb][reg] * inv);
    }
}

// ---------------------------------------------------------------------------
extern "C" void kernel_launch(void* const* d_in, const int* in_sizes, int n_in,
                              void* d_out, int out_size, void* d_ws, size_t ws_size,
                              hipStream_t stream)
{
    const float* x  = (const float*)d_in[0];
    const float* Wq = (const float*)d_in[1];
    const float* Wk = (const float*)d_in[2];
    const float* Wv = (const float*)d_in[3];
    const float* Wo = (const float*)d_in[4];
    const float* bo = (const float*)d_in[5];
    const float* lw = (const float*)d_in[6];
    float* out = (float*)d_out;

    const size_t SZ  = (size_t)BB * TT * INNER;  // 2M elements
    const size_t NWE = (size_t)DD * INNER;       // 256K per weight
    ushort_t* xb    = (ushort_t*)d_ws;
    ushort_t* wqkvt = xb + SZ;                   // fused [1536][512]
    ushort_t* wot   = wqkvt + 3 * NWE;
    ushort_t* q     = wot + NWE;
    ushort_t* k     = q + SZ;
    ushort_t* vt    = k + SZ;                    // V TRANSPOSED [bh][d][t]
    ushort_t* ao    = xb;                        // alias: xb dead after QKV

    cvt_kernel<<<2048, 256, 0, stream>>>(x, Wq, Wk, Wv, Wo, xb, wqkvt, wot);

    dim3 gQKV(3 * INNER / QN, (BB * TT) / QM);   // (24, 32) = 768 blocks
    gemm_qkv<<<gQKV, 256, 0, stream>>>(xb, wqkvt, q, k, vt);

    dim3 gATT(32, BB * HH);                      // 512 blocks = 2/CU
    attn_mfma<<<gATT, 256, 0, stream>>>(q, k, vt, lw, ao);

    dim3 gPRJ(DD / 64, (BB * TT) / 64);          // (8, 64) = 512 blocks
    gemm_proj<<<gPRJ, 256, 0, stream>>>(ao, wot, out, bo);
}